// Round 1
// baseline (277.177 us; speedup 1.0000x reference)
//
#include <hip/hip_runtime.h>
#include <cstdint>
#include <cstddef>

// ---------------- problem constants ----------------
#define NPIX   4096
#define SCALE  0.08838834764831845f   // 128^-0.5
#define EPS_   1e-8f
#define LN_EPS_ 1e-5f

// ---------------- workspace layout (float offsets) ----------------
// total = 8,454,912 floats = 33.8 MB
constexpr int OFF_WKF   = 0;          // 16384  (f_w1@Wk folded)
constexpr int OFF_WVF   = 16384;      // 16384
constexpr int OFF_GFD   = 32768;      // 256    ((f_w1@g_w)/DELTA, [h][2])
constexpr int OFF_CB    = 33024;      // 128    (f_w1@g_b + f_b1)
constexpr int OFF_QF    = 33152;      // 8192   (scale * f_w2^T q, per b,s)
constexpr int OFF_QB    = 41344;      // 64     (scale * q.f_b2)
constexpr int OFF_OF    = 41408;      // 8192   (-S_p . GFD, per b,s)
constexpr int OFF_SLOTS = 49600;      // 8192
constexpr int OFF_SP    = 57792;      // 128
constexpr int OFF_U     = 57920;      // 8192   accumulators (memset / iter)
constexpr int OFF_Z     = 66112;      // 64
constexpr int OFF_P     = 66176;      // 128
constexpr int OFF_BASEK = 66304;      // 4,194,304
constexpr int OFF_BASEV = 66304 + 4194304;

__device__ __forceinline__ float waveReduceSum(float v) {
#pragma unroll
  for (int m = 1; m < 64; m <<= 1) v += __shfl_xor(v, m, 64);
  return v;
}

// ---------------- kernel: fold weights ----------------
// WKF[h,e] = sum_d f_w1[h,d]*Wk[d,e]; WVF likewise; GFD[h,c] = (f_w1@g_w)/DELTA;
// CB[h] = f_w1@g_b + f_b1
__global__ __launch_bounds__(256) void kFold(
    const float* __restrict__ f_w1, const float* __restrict__ Wk,
    const float* __restrict__ Wv, const float* __restrict__ g_w,
    const float* __restrict__ g_b, const float* __restrict__ f_b1,
    float* __restrict__ ws) {
  int blk = blockIdx.x, tid = threadIdx.x;
  if (blk < 128) {
    int isV = blk >> 6;
    int idx = (blk & 63) * 256 + tid;           // 0..16383
    int h = idx >> 7, e = idx & 127;
    const float* Wm = isV ? Wv : Wk;
    float a = 0.f;
#pragma unroll 4
    for (int d = 0; d < 128; ++d) a = fmaf(f_w1[h * 128 + d], Wm[d * 128 + e], a);
    ws[(isV ? OFF_WVF : OFF_WKF) + idx] = a;
  } else if (blk == 128) {
    int h = tid >> 1, c = tid & 1;
    float a = 0.f;
    for (int d = 0; d < 128; ++d) a = fmaf(f_w1[h * 128 + d], g_w[d * 2 + c], a);
    ws[OFF_GFD + tid] = a * 0.2f;               // /DELTA (DELTA=5)
  } else {
    if (tid < 128) {
      float a = f_b1[tid];
      for (int d = 0; d < 128; ++d) a = fmaf(f_w1[tid * 128 + d], g_b[d], a);
      ws[OFF_CB + tid] = a;
    }
  }
}

// ---------------- kernel: base GEMMs ----------------
// base_{k,v}[row, c] = inputs[row,:] . W{K,V}F[c,:] + gy*GFD[c,0] + gx*GFD[c,1] + CB[c]
// grid: (256 row-blocks of 128 rows, 2), block 256
__global__ __launch_bounds__(256) void kBase(const float* __restrict__ inputs,
                                             float* __restrict__ ws) {
  __shared__ float WL[128 * 128];               // 64 KiB
  int tid = threadIdx.x;
  int isV = blockIdx.y;
  const float* Wf = ws + (isV ? OFF_WVF : OFF_WKF);
  float* out = ws + (isV ? OFF_BASEV : OFF_BASEK);
  for (int i = tid; i < 16384; i += 256) WL[i] = Wf[i];
  __syncthreads();
  int rg = tid & 15, cg = tid >> 4;             // 16 row-groups x 16 ch-groups
  int rowbase = blockIdx.x * 128;
  float gf0[8], gf1[8], cbl[8];
#pragma unroll
  for (int j = 0; j < 8; ++j) {
    int c = cg * 8 + j;
    gf0[j] = ws[OFF_GFD + c * 2 + 0];
    gf1[j] = ws[OFF_GFD + c * 2 + 1];
    cbl[j] = ws[OFF_CB + c];
  }
  float acc[8][8];
#pragma unroll
  for (int r = 0; r < 8; ++r)
#pragma unroll
    for (int j = 0; j < 8; ++j) acc[r][j] = 0.f;
  const float* inp = inputs + (size_t)rowbase * 128;
  for (int e4 = 0; e4 < 32; ++e4) {
    float4 iv[8], wv[8];
#pragma unroll
    for (int r = 0; r < 8; ++r)
      iv[r] = *(const float4*)&inp[(r * 16 + rg) * 128 + e4 * 4];
#pragma unroll
    for (int j = 0; j < 8; ++j)
      wv[j] = *(const float4*)&WL[(cg * 8 + j) * 128 + e4 * 4];
#pragma unroll
    for (int r = 0; r < 8; ++r)
#pragma unroll
      for (int j = 0; j < 8; ++j) {
        acc[r][j] = fmaf(iv[r].x, wv[j].x, acc[r][j]);
        acc[r][j] = fmaf(iv[r].y, wv[j].y, acc[r][j]);
        acc[r][j] = fmaf(iv[r].z, wv[j].z, acc[r][j]);
        acc[r][j] = fmaf(iv[r].w, wv[j].w, acc[r][j]);
      }
  }
#pragma unroll
  for (int r = 0; r < 8; ++r) {
    int grow = rowbase + r * 16 + rg;
    int n = grow & 4095;
    float gy = -1.f + (float)(n >> 6) * (2.f / 63.f);
    float gx = -1.f + (float)(n & 63) * (2.f / 63.f);
    float o[8];
#pragma unroll
    for (int j = 0; j < 8; ++j)
      o[j] = acc[r][j] + gy * gf0[j] + gx * gf1[j] + cbl[j];
    float4* dst = (float4*)(out + (size_t)grow * 128 + cg * 8);
    dst[0] = make_float4(o[0], o[1], o[2], o[3]);
    dst[1] = make_float4(o[4], o[5], o[6], o[7]);
  }
}

// ---------------- kernel: per-(b,s) q projection + offsets ----------------
__global__ __launch_bounds__(128) void kQ(
    const float* __restrict__ Wq, const float* __restrict__ f_w2,
    const float* __restrict__ f_b2, const float* __restrict__ ln_g,
    const float* __restrict__ ln_b, float* __restrict__ ws) {
  int bs = blockIdx.x;      // b*8+s
  int d = threadIdx.x;
  int wid = d >> 6, lane = d & 63;
  __shared__ float red[4];
  __shared__ float sn[128], ql[128];
  float x = ws[OFF_SLOTS + bs * 128 + d];
  float s1 = waveReduceSum(x);
  if (lane == 0) red[wid] = s1;
  __syncthreads();
  float mean = (red[0] + red[1]) * (1.f / 128.f);
  float dx = x - mean;
  float s2 = waveReduceSum(dx * dx);
  if (lane == 0) red[2 + wid] = s2;
  __syncthreads();
  float var = (red[2] + red[3]) * (1.f / 128.f);
  float y = dx * rsqrtf(var + LN_EPS_) * ln_g[d] + ln_b[d];
  sn[d] = y;
  __syncthreads();
  float q = 0.f;
#pragma unroll 8
  for (int e = 0; e < 128; ++e) q = fmaf(sn[e], Wq[d * 128 + e], q);
  ql[d] = q;
  __syncthreads();
  float qf = 0.f;
#pragma unroll 8
  for (int e = 0; e < 128; ++e) qf = fmaf(ql[e], f_w2[e * 128 + d], qf);
  ws[OFF_QF + bs * 128 + d] = qf * SCALE;
  float t = ql[d] * f_b2[d];
  float sq = waveReduceSum(t);
  if (lane == 0) red[wid] = sq;
  __syncthreads();
  if (d == 0) ws[OFF_QB + bs] = (red[0] + red[1]) * SCALE;
  float sp0 = ws[OFF_SP + bs * 2 + 0], sp1 = ws[OFF_SP + bs * 2 + 1];
  ws[OFF_OF + bs * 128 + d] =
      -(sp0 * ws[OFF_GFD + d * 2 + 0] + sp1 * ws[OFF_GFD + d * 2 + 1]);
}

// ---------------- kernel: fused dots/softmax/update accumulation ----------------
// grid 512 (=8 b * 64 chunks), block 256 (4 waves x 16 pixels each)
__global__ __launch_bounds__(256) void kAttn(float* __restrict__ ws) {
  int b = blockIdx.x >> 6, chunk = blockIdx.x & 63;
  int wid = threadIdx.x >> 6, lane = threadIdx.x & 63;
  int sb = b * 8;
  const float* BK = ws + OFF_BASEK;
  const float* BV = ws + OFF_BASEV;
  float2 offv[8], qfv[8];
  float qbl[8];
#pragma unroll
  for (int s = 0; s < 8; ++s) {
    offv[s] = *(const float2*)(ws + OFF_OF + (sb + s) * 128 + 2 * lane);
    qfv[s]  = *(const float2*)(ws + OFF_QF + (sb + s) * 128 + 2 * lane);
    qbl[s]  = ws[OFF_QB + sb + s];
  }
  float Ua0[8], Ua1[8], Zall[8], Pall0[8], Pall1[8];
#pragma unroll
  for (int s = 0; s < 8; ++s) {
    Ua0[s] = 0.f; Ua1[s] = 0.f; Zall[s] = 0.f; Pall0[s] = 0.f; Pall1[s] = 0.f;
  }
  int n0 = chunk * 64 + wid * 16;
  size_t rbase = ((size_t)(b * 4096 + n0)) * 128 + 2 * lane;
  float2 bk = *(const float2*)(BK + rbase);
  float2 bv = *(const float2*)(BV + rbase);
  for (int i = 0; i < 16; ++i) {
    float2 nbk, nbv;
    if (i < 15) {
      nbk = *(const float2*)(BK + rbase + (size_t)(i + 1) * 128);
      nbv = *(const float2*)(BV + rbase + (size_t)(i + 1) * 128);
    }
    float t[8];
#pragma unroll
    for (int s = 0; s < 8; ++s)
      t[s] = fmaxf(bk.x + offv[s].x, 0.f) * qfv[s].x +
             fmaxf(bk.y + offv[s].y, 0.f) * qfv[s].y;
#pragma unroll
    for (int s = 0; s < 8; ++s) {
#pragma unroll
      for (int m = 1; m < 64; m <<= 1) t[s] += __shfl_xor(t[s], m, 64);
      t[s] += qbl[s];
    }
    float mx = t[0];
#pragma unroll
    for (int s = 1; s < 8; ++s) mx = fmaxf(mx, t[s]);
    float at[8], den = 0.f;
#pragma unroll
    for (int s = 0; s < 8; ++s) { at[s] = __expf(t[s] - mx); den += at[s]; }
    float inv = 1.0f / den;
    int n = n0 + i;
    float gy = -1.f + (float)(n >> 6) * (2.f / 63.f);
    float gx = -1.f + (float)(n & 63) * (2.f / 63.f);
#pragma unroll
    for (int s = 0; s < 8; ++s) {
      float a = fmaf(at[s], inv, EPS_);
      Zall[s] += a;
      Pall0[s] = fmaf(a, gy, Pall0[s]);
      Pall1[s] = fmaf(a, gx, Pall1[s]);
      Ua0[s] = fmaf(a, fmaxf(bv.x + offv[s].x, 0.f), Ua0[s]);
      Ua1[s] = fmaf(a, fmaxf(bv.y + offv[s].y, 0.f), Ua1[s]);
    }
    bk = nbk; bv = nbv;
  }
  // block-level reduction then global atomics
  __shared__ float Ush[4][8][128];
  __shared__ float Zsh[4][8], Psh0[4][8], Psh1[4][8];
#pragma unroll
  for (int s = 0; s < 8; ++s)
    *(float2*)&Ush[wid][s][2 * lane] = make_float2(Ua0[s], Ua1[s]);
  if (lane == 0) {
#pragma unroll
    for (int s = 0; s < 8; ++s) {
      Zsh[wid][s] = Zall[s]; Psh0[wid][s] = Pall0[s]; Psh1[wid][s] = Pall1[s];
    }
  }
  __syncthreads();
  int tid = threadIdx.x;
  for (int idx = tid; idx < 1024; idx += 256) {
    int s = idx >> 7, c = idx & 127;
    float v = Ush[0][s][c] + Ush[1][s][c] + Ush[2][s][c] + Ush[3][s][c];
    atomicAdd(&ws[OFF_U + (sb + s) * 128 + c], v);
  }
  if (tid < 8) {
    atomicAdd(&ws[OFF_Z + sb + tid],
              Zsh[0][tid] + Zsh[1][tid] + Zsh[2][tid] + Zsh[3][tid]);
  } else if (tid < 16) {
    int s = tid - 8;
    atomicAdd(&ws[OFF_P + (sb + s) * 2 + 0],
              Psh0[0][s] + Psh0[1][s] + Psh0[2][s] + Psh0[3][s]);
  } else if (tid < 24) {
    int s = tid - 16;
    atomicAdd(&ws[OFF_P + (sb + s) * 2 + 1],
              Psh1[0][s] + Psh1[1][s] + Psh1[2][s] + Psh1[3][s]);
  }
}

// ---------------- kernel: finalize updates + GRU + post-MLP ----------------
__global__ __launch_bounds__(128) void kC(
    const float* __restrict__ f_w2, const float* __restrict__ f_b2,
    const float* __restrict__ wih, const float* __restrict__ whh,
    const float* __restrict__ bih, const float* __restrict__ bhh,
    const float* __restrict__ mw1, const float* __restrict__ mb1,
    const float* __restrict__ mw2, const float* __restrict__ mb2,
    const float* __restrict__ lng, const float* __restrict__ lnb,
    float* __restrict__ ws) {
  int bs = blockIdx.x, d = threadIdx.x;
  int wid = d >> 6, lane = d & 63;
  __shared__ float red[4];
  __shared__ float ul[128], xl[128], hl[128], yl[128], hml[128];
  float Z = ws[OFF_Z + bs];
  float invZ = 1.0f / Z;
  ul[d] = ws[OFF_U + bs * 128 + d] * invZ;
  if (d < 2) ws[OFF_SP + bs * 2 + d] = ws[OFF_P + bs * 2 + d] * invZ;
  float hprev = ws[OFF_SLOTS + bs * 128 + d];
  hl[d] = hprev;
  __syncthreads();
  float upd = f_b2[d];
#pragma unroll 8
  for (int e = 0; e < 128; ++e) upd = fmaf(ul[e], f_w2[d * 128 + e], upd);
  xl[d] = upd;
  __syncthreads();
  float ir = bih[d], iz = bih[128 + d], inn = bih[256 + d];
  float hr = bhh[d], hz = bhh[128 + d], hn = bhh[256 + d];
#pragma unroll 4
  for (int e = 0; e < 128; ++e) {
    float xe = xl[e], he = hl[e];
    ir = fmaf(xe, wih[d * 128 + e], ir);
    iz = fmaf(xe, wih[(128 + d) * 128 + e], iz);
    inn = fmaf(xe, wih[(256 + d) * 128 + e], inn);
    hr = fmaf(he, whh[d * 128 + e], hr);
    hz = fmaf(he, whh[(128 + d) * 128 + e], hz);
    hn = fmaf(he, whh[(256 + d) * 128 + e], hn);
  }
  float r = 1.f / (1.f + __expf(-(ir + hr)));
  float z = 1.f / (1.f + __expf(-(iz + hz)));
  float nn = tanhf(inn + r * hn);
  float hnew = (1.f - z) * nn + z * hprev;
  // LayerNorm(hnew) with ln_pf
  float s1 = waveReduceSum(hnew);
  if (lane == 0) red[wid] = s1;
  __syncthreads();
  float mean = (red[0] + red[1]) * (1.f / 128.f);
  float dx = hnew - mean;
  float s2 = waveReduceSum(dx * dx);
  if (lane == 0) red[2 + wid] = s2;
  __syncthreads();
  float var = (red[2] + red[3]) * (1.f / 128.f);
  float y = dx * rsqrtf(var + LN_EPS_) * lng[d] + lnb[d];
  yl[d] = y;
  __syncthreads();
  float hm = mb1[d];
#pragma unroll 8
  for (int e = 0; e < 128; ++e) hm = fmaf(yl[e], mw1[d * 128 + e], hm);
  hml[d] = fmaxf(hm, 0.f);
  __syncthreads();
  float o = hnew + mb2[d];
#pragma unroll 8
  for (int e = 0; e < 128; ++e) o = fmaf(hml[e], mw2[d * 128 + e], o);
  ws[OFF_SLOTS + bs * 128 + d] = o;
}

// ---------------- kernel: write outputs ----------------
__global__ __launch_bounds__(256) void kOut(const float* __restrict__ ws,
                                            const float* __restrict__ S_r,
                                            const float* __restrict__ S_s,
                                            float* __restrict__ out) {
  int i = blockIdx.x * 256 + threadIdx.x;
  if (i < 8192) out[i] = ws[OFF_SLOTS + i];
  else if (i < 8320) out[i] = ws[OFF_SP + i - 8192];
  else if (i < 8576) out[i] = S_r[i - 8320];
  else if (i < 8704) out[i] = S_s[i - 8576];
}

extern "C" void kernel_launch(void* const* d_in, const int* in_sizes, int n_in,
                              void* d_out, int out_size, void* d_ws, size_t ws_size,
                              hipStream_t stream) {
  const float* inputs     = (const float*)d_in[0];
  const float* slots_init = (const float*)d_in[1];
  const float* S_p0       = (const float*)d_in[2];
  const float* S_s        = (const float*)d_in[3];
  const float* S_r        = (const float*)d_in[4];
  const float* Wq   = (const float*)d_in[5];
  const float* Wk   = (const float*)d_in[6];
  const float* Wv   = (const float*)d_in[7];
  const float* g_w  = (const float*)d_in[8];
  const float* g_b  = (const float*)d_in[9];
  const float* f_w1 = (const float*)d_in[10];
  const float* f_b1 = (const float*)d_in[11];
  const float* f_w2 = (const float*)d_in[12];
  const float* f_b2 = (const float*)d_in[13];
  const float* gwih = (const float*)d_in[14];
  const float* gwhh = (const float*)d_in[15];
  const float* gbih = (const float*)d_in[16];
  const float* gbhh = (const float*)d_in[17];
  const float* mw1  = (const float*)d_in[18];
  const float* mb1  = (const float*)d_in[19];
  const float* mw2  = (const float*)d_in[20];
  const float* mb2  = (const float*)d_in[21];
  const float* lnsg = (const float*)d_in[22];
  const float* lnsb = (const float*)d_in[23];
  const float* lnpg = (const float*)d_in[24];
  const float* lnpb = (const float*)d_in[25];
  float* ws  = (float*)d_ws;
  float* out = (float*)d_out;

  hipMemcpyAsync(ws + OFF_SLOTS, slots_init, 8192 * sizeof(float),
                 hipMemcpyDeviceToDevice, stream);
  hipMemcpyAsync(ws + OFF_SP, S_p0, 128 * sizeof(float),
                 hipMemcpyDeviceToDevice, stream);
  kFold<<<130, 256, 0, stream>>>(f_w1, Wk, Wv, g_w, g_b, f_b1, ws);
  kBase<<<dim3(256, 2), 256, 0, stream>>>(inputs, ws);
  for (int it = 0; it < 3; ++it) {
    kQ<<<64, 128, 0, stream>>>(Wq, f_w2, f_b2, lnsg, lnsb, ws);
    hipMemsetAsync(ws + OFF_U, 0, 8384 * sizeof(float), stream);
    kAttn<<<512, 256, 0, stream>>>(ws);
    kC<<<64, 128, 0, stream>>>(f_w2, f_b2, gwih, gwhh, gbih, gbhh,
                               mw1, mb1, mw2, mb2, lnpg, lnpb, ws);
  }
  kOut<<<35, 256, 0, stream>>>(ws, S_r, S_s, out);
}